// Round 3
// baseline (146.970 us; speedup 1.0000x reference)
//
#include <hip/hip_runtime.h>
#include <math.h>

#define N 4096
#define NB 2
#define THRESHOLD_FACTOR 1.25
#define PB 16  // partial-sum blocks per batch (each block covers 256 points)

// native clang vector type so __builtin_nontemporal_store accepts it
typedef float floatx4 __attribute__((ext_vector_type(4)));

// ---------------------------------------------------------------------------
// Workspace layout: [0..7]   : float thr[2]   (8 B, padded)
//                   [64.. ]  : double part[NB*10*PB]  (2.5 KB)
// ---------------------------------------------------------------------------

// ---------------------------------------------------------------------------
// Stage 1: wide partial sums. dist[s,t] = a_s*A_t + b_s*B_t with a=x^2, b=y^2,
// A=(1-x)^2, B=(1-y)^2 (separable), so mean/std need only 10 per-batch sums:
//   sum d   = Sa*SA + Sb*SB
//   sum d^2 = Saa*SAA + Sbb*SBB + 2*Sab*SAB
// 32 blocks x 256 threads, one point per thread, wave shuffle reduce + LDS.
// ---------------------------------------------------------------------------
__global__ __launch_bounds__(256) void stats_partial(const float* __restrict__ r,
                                                     double* __restrict__ part) {
    int blk = blockIdx.x;            // 0 .. NB*PB-1
    int b = blk >> 4;                // PB = 16
    int chunk = blk & 15;
    int tid = threadIdx.x;
    int idx = chunk * 256 + tid;     // 0..4095

    const float2* rb2 = (const float2*)(r + (size_t)b * N * 2);
    float2 p = rb2[idx];
    double x = (double)p.x, y = (double)p.y;
    double a  = x * x;
    double bb = y * y;
    double ax = 1.0 - x, by = 1.0 - y;
    double A  = ax * ax;
    double Bv = by * by;
    double s[10] = {a, bb, A, Bv, a * a, bb * bb, a * bb, A * A, Bv * Bv, A * Bv};

    // wave64 shuffle reduction for each quantity
#pragma unroll
    for (int q = 0; q < 10; ++q) {
        double v = s[q];
#pragma unroll
        for (int off = 32; off > 0; off >>= 1) v += __shfl_down(v, off, 64);
        s[q] = v;
    }

    __shared__ double wred[4][10];
    int lane = tid & 63, wid = tid >> 6;
    if (lane == 0) {
#pragma unroll
        for (int q = 0; q < 10; ++q) wred[wid][q] = s[q];
    }
    __syncthreads();
    if (tid == 0) {
#pragma unroll
        for (int q = 0; q < 10; ++q)
            part[(b * 10 + q) * PB + chunk] =
                wred[0][q] + wred[1][q] + wred[2][q] + wred[3][q];
    }
}

// ---------------------------------------------------------------------------
// Stage 2: one tiny block folds the 16 partials per (batch, quantity) and
// computes thr[b] = mean + 1.25 * std (unbiased, n-1).
// 320 threads = 20 groups of 16 lanes, shuffle-reduce within group.
// ---------------------------------------------------------------------------
__global__ __launch_bounds__(320) void stats_final(const double* __restrict__ part,
                                                   float* __restrict__ thr) {
    int tid = threadIdx.x;           // 0..319, exactly NB*10*PB entries
    double v = part[tid];
#pragma unroll
    for (int off = 8; off > 0; off >>= 1) v += __shfl_down(v, off, 16);
    __shared__ double sums[20];
    if ((tid & 15) == 0) sums[tid >> 4] = v;
    __syncthreads();
    if (tid < NB) {
        const double* t = &sums[tid * 10];
        double pairs = (double)N * (double)N;
        double sum_d  = t[0] * t[2] + t[1] * t[3];
        double sum_d2 = t[4] * t[7] + t[5] * t[8] + 2.0 * t[6] * t[9];
        double mean = sum_d / pairs;
        double var = (sum_d2 - sum_d * sum_d / pairs) / (pairs - 1.0);
        double sd = sqrt(var);
        if (sd < 1e-6) sd = 1e-6;
        thr[tid] = (float)(mean + THRESHOLD_FACTOR * sd);
    }
}

// ---------------------------------------------------------------------------
// Kernel 3: one block per PAIR of rows (b,s0),(b,s0+1); two rows share every
// t-point load. Output stores are NON-TEMPORAL: the 128 MiB result is written
// once and never read, so L2 write-allocate is pure pollution (32 MiB L2).
// ---------------------------------------------------------------------------
__device__ inline void nt_store4(float* p, float x, float y, float z, float w) {
    floatx4 v = {x, y, z, w};
    __builtin_nontemporal_store(v, (floatx4*)p);
}

__global__ __launch_bounds__(256) void attn_kernel(const float* __restrict__ r,
                                                   const float* __restrict__ thr,
                                                   float* __restrict__ out) {
    int blk = blockIdx.x;              // 0 .. NB*2048-1
    int b = blk >> 11;                 // 2048 blocks per batch
    int s0 = (blk & 2047) << 1;        // rows s0, s0+1
    const float* rb = r + (size_t)b * N * 2;

    float4 rs = *(const float4*)(rb + (size_t)s0 * 2);
    float ax = rs.x, ay = rs.y;        // row A = s0
    float bx = rs.z, by = rs.w;        // row B = s0+1
    float threshold = thr[b];

    int tid = threadIdx.x;
    float va[16], vb[16];
    float sumA = 0.0f, sumB = 0.0f;

#pragma unroll
    for (int g = 0; g < 4; ++g) {
        int t0 = g * 1024 + tid * 4;
        float4 p0 = *(const float4*)(rb + (size_t)t0 * 2);
        float4 p1 = *(const float4*)(rb + (size_t)t0 * 2 + 4);
        float tx[4] = {p0.x, p0.z, p1.x, p1.z};
        float ty[4] = {p0.y, p0.w, p1.y, p1.w};
#pragma unroll
        for (int k = 0; k < 4; ++k) {
            // ---- row A ----
            float dxA = fmaf(-ax, tx[k], ax);
            float dyA = fmaf(-ay, ty[k], ay);
            float dA  = fmaf(dxA, dxA, dyA * dyA);
            float cA  = (dA > 0.0f) ? dxA * __builtin_amdgcn_rsqf(dA) : 1.0f;
            float eA  = 0.5f * __expf(-dA);
            float fbA = fmaf(cA, eA, eA);          // 0.5*(1+c)*exp(-d)
            float vA  = (dA <= threshold) ? fbA : 0.0f;
            va[g * 4 + k] = vA;
            sumA += vA;
            // ---- row B (shares tx,ty) ----
            float dxB = fmaf(-bx, tx[k], bx);
            float dyB = fmaf(-by, ty[k], by);
            float dB  = fmaf(dxB, dxB, dyB * dyB);
            float cB  = (dB > 0.0f) ? dxB * __builtin_amdgcn_rsqf(dB) : 1.0f;
            float eB  = 0.5f * __expf(-dB);
            float fbB = fmaf(cB, eB, eB);
            float vB  = (dB <= threshold) ? fbB : 0.0f;
            vb[g * 4 + k] = vB;
            sumB += vB;
        }
    }

#pragma unroll
    for (int off = 32; off > 0; off >>= 1) {
        sumA += __shfl_down(sumA, off, 64);
        sumB += __shfl_down(sumB, off, 64);
    }
    __shared__ float wsum[2][4];
    int lane = tid & 63;
    int wid = tid >> 6;
    if (lane == 0) { wsum[0][wid] = sumA; wsum[1][wid] = sumB; }
    __syncthreads();
    float totA = wsum[0][0] + wsum[0][1] + wsum[0][2] + wsum[0][3];
    float totB = wsum[1][0] + wsum[1][1] + wsum[1][2] + wsum[1][3];
    float invA = __builtin_amdgcn_rcpf(totA + 1e-8f);
    float invB = __builtin_amdgcn_rcpf(totB + 1e-8f);

    size_t rowA = ((size_t)b * N + (size_t)s0) * N;
    float* outA = out + rowA;
    float* outB = out + rowA + N;
#pragma unroll
    for (int g = 0; g < 4; ++g) {
        int t0 = g * 1024 + tid * 4;
        nt_store4(outA + t0,
                  va[g * 4 + 0] * invA, va[g * 4 + 1] * invA,
                  va[g * 4 + 2] * invA, va[g * 4 + 3] * invA);
        nt_store4(outB + t0,
                  vb[g * 4 + 0] * invB, vb[g * 4 + 1] * invB,
                  vb[g * 4 + 2] * invB, vb[g * 4 + 3] * invB);
    }
}

extern "C" void kernel_launch(void* const* d_in, const int* in_sizes, int n_in,
                              void* d_out, int out_size, void* d_ws, size_t ws_size,
                              hipStream_t stream) {
    const float* r = (const float*)d_in[0];
    float* out = (float*)d_out;
    float* thr = (float*)d_ws;
    double* part = (double*)((char*)d_ws + 64);

    stats_partial<<<NB * PB, 256, 0, stream>>>(r, part);
    stats_final<<<1, 320, 0, stream>>>(part, thr);
    attn_kernel<<<NB * 2048, 256, 0, stream>>>(r, thr, out);
}

// Round 4
// 144.152 us; speedup vs baseline: 1.0196x; 1.0196x over previous
//
#include <hip/hip_runtime.h>
#include <math.h>

#define N 4096
#define NB 2
#define THRESHOLD_FACTOR 1.25
#define PB 16  // partial-sum blocks per batch (each block covers 256 points)

// native clang vector type so __builtin_nontemporal_store accepts it
typedef float floatx4 __attribute__((ext_vector_type(4)));

// ---------------------------------------------------------------------------
// Workspace layout: [64.. ] : double part[NB*10*PB]  (2.5 KB)
// ---------------------------------------------------------------------------

// ---------------------------------------------------------------------------
// Stage 1: wide partial sums. dist[s,t] = a_s*A_t + b_s*B_t with a=x^2, b=y^2,
// A=(1-x)^2, B=(1-y)^2 (separable), so mean/std need only 10 per-batch sums:
//   sum d   = Sa*SA + Sb*SB
//   sum d^2 = Saa*SAA + Sbb*SBB + 2*Sab*SAB
// 32 blocks x 256 threads, one point per thread, wave shuffle reduce + LDS.
// ---------------------------------------------------------------------------
__global__ __launch_bounds__(256) void stats_partial(const float* __restrict__ r,
                                                     double* __restrict__ part) {
    int blk = blockIdx.x;            // 0 .. NB*PB-1
    int b = blk >> 4;                // PB = 16
    int chunk = blk & 15;
    int tid = threadIdx.x;
    int idx = chunk * 256 + tid;     // 0..4095

    const float2* rb2 = (const float2*)(r + (size_t)b * N * 2);
    float2 p = rb2[idx];
    double x = (double)p.x, y = (double)p.y;
    double a  = x * x;
    double bb = y * y;
    double ax = 1.0 - x, by = 1.0 - y;
    double A  = ax * ax;
    double Bv = by * by;
    double s[10] = {a, bb, A, Bv, a * a, bb * bb, a * bb, A * A, Bv * Bv, A * Bv};

    // wave64 shuffle reduction for each quantity
#pragma unroll
    for (int q = 0; q < 10; ++q) {
        double v = s[q];
#pragma unroll
        for (int off = 32; off > 0; off >>= 1) v += __shfl_down(v, off, 64);
        s[q] = v;
    }

    __shared__ double wred[4][10];
    int lane = tid & 63, wid = tid >> 6;
    if (lane == 0) {
#pragma unroll
        for (int q = 0; q < 10; ++q) wred[wid][q] = s[q];
    }
    __syncthreads();
    if (tid == 0) {
#pragma unroll
        for (int q = 0; q < 10; ++q)
            part[(b * 10 + q) * PB + chunk] =
                wred[0][q] + wred[1][q] + wred[2][q] + wred[3][q];
    }
}

// ---------------------------------------------------------------------------
// Kernel 2: one block per PAIR of rows (b,s0),(b,s0+1). Preamble folds the
// 160 partial sums for this batch (2.5 KB, L2 broadcast) and computes the
// threshold locally — eliminates the former 1-block stats_final kernel and
// its launch/serialization (255 idle CUs on the critical path).
// Two rows share every t-point load; stores are non-temporal (output is
// written once, never read — no L2 write-allocate).
// ---------------------------------------------------------------------------
__device__ inline void nt_store4(float* p, float x, float y, float z, float w) {
    floatx4 v = {x, y, z, w};
    __builtin_nontemporal_store(v, (floatx4*)p);
}

__global__ __launch_bounds__(256) void attn_kernel(const float* __restrict__ r,
                                                   const double* __restrict__ part,
                                                   float* __restrict__ out) {
    int blk = blockIdx.x;              // 0 .. NB*2048-1
    int b = blk >> 11;                 // 2048 blocks per batch
    int s0 = (blk & 2047) << 1;        // rows s0, s0+1
    const float* rb = r + (size_t)b * N * 2;
    int tid = threadIdx.x;

    // ---- fold this batch's 160 partials -> 10 sums -> threshold ----
    __shared__ double sred[10];
    if (tid < 160) {
        int q = tid >> 4;              // quantity 0..9
        int c = tid & 15;              // chunk 0..15 (16-lane group, intra-wave)
        double v = part[(b * 10 + q) * PB + c];
#pragma unroll
        for (int off = 8; off > 0; off >>= 1) v += __shfl_down(v, off, 16);
        if (c == 0) sred[q] = v;
    }
    __syncthreads();
    double pairs = (double)N * (double)N;
    double sum_d  = sred[0] * sred[2] + sred[1] * sred[3];
    double sum_d2 = sred[4] * sred[7] + sred[5] * sred[8] + 2.0 * sred[6] * sred[9];
    double mean = sum_d / pairs;
    double var = (sum_d2 - sum_d * sum_d / pairs) / (pairs - 1.0);
    double sd = sqrt(var);
    if (sd < 1e-6) sd = 1e-6;
    float threshold = (float)(mean + THRESHOLD_FACTOR * sd);

    // ---- main row-pair loop ----
    float4 rs = *(const float4*)(rb + (size_t)s0 * 2);
    float ax = rs.x, ay = rs.y;        // row A = s0
    float bx = rs.z, by = rs.w;        // row B = s0+1

    float va[16], vb[16];
    float sumA = 0.0f, sumB = 0.0f;

#pragma unroll
    for (int g = 0; g < 4; ++g) {
        int t0 = g * 1024 + tid * 4;
        float4 p0 = *(const float4*)(rb + (size_t)t0 * 2);
        float4 p1 = *(const float4*)(rb + (size_t)t0 * 2 + 4);
        float tx[4] = {p0.x, p0.z, p1.x, p1.z};
        float ty[4] = {p0.y, p0.w, p1.y, p1.w};
#pragma unroll
        for (int k = 0; k < 4; ++k) {
            // ---- row A ----
            float dxA = fmaf(-ax, tx[k], ax);
            float dyA = fmaf(-ay, ty[k], ay);
            float dA  = fmaf(dxA, dxA, dyA * dyA);
            float cA  = (dA > 0.0f) ? dxA * __builtin_amdgcn_rsqf(dA) : 1.0f;
            float eA  = 0.5f * __expf(-dA);
            float fbA = fmaf(cA, eA, eA);          // 0.5*(1+c)*exp(-d)
            float vA  = (dA <= threshold) ? fbA : 0.0f;
            va[g * 4 + k] = vA;
            sumA += vA;
            // ---- row B (shares tx,ty) ----
            float dxB = fmaf(-bx, tx[k], bx);
            float dyB = fmaf(-by, ty[k], by);
            float dB  = fmaf(dxB, dxB, dyB * dyB);
            float cB  = (dB > 0.0f) ? dxB * __builtin_amdgcn_rsqf(dB) : 1.0f;
            float eB  = 0.5f * __expf(-dB);
            float fbB = fmaf(cB, eB, eB);
            float vB  = (dB <= threshold) ? fbB : 0.0f;
            vb[g * 4 + k] = vB;
            sumB += vB;
        }
    }

#pragma unroll
    for (int off = 32; off > 0; off >>= 1) {
        sumA += __shfl_down(sumA, off, 64);
        sumB += __shfl_down(sumB, off, 64);
    }
    __shared__ float wsum[2][4];
    int lane = tid & 63;
    int wid = tid >> 6;
    if (lane == 0) { wsum[0][wid] = sumA; wsum[1][wid] = sumB; }
    __syncthreads();
    float totA = wsum[0][0] + wsum[0][1] + wsum[0][2] + wsum[0][3];
    float totB = wsum[1][0] + wsum[1][1] + wsum[1][2] + wsum[1][3];
    float invA = __builtin_amdgcn_rcpf(totA + 1e-8f);
    float invB = __builtin_amdgcn_rcpf(totB + 1e-8f);

    size_t rowA = ((size_t)b * N + (size_t)s0) * N;
    float* outA = out + rowA;
    float* outB = out + rowA + N;
#pragma unroll
    for (int g = 0; g < 4; ++g) {
        int t0 = g * 1024 + tid * 4;
        nt_store4(outA + t0,
                  va[g * 4 + 0] * invA, va[g * 4 + 1] * invA,
                  va[g * 4 + 2] * invA, va[g * 4 + 3] * invA);
        nt_store4(outB + t0,
                  vb[g * 4 + 0] * invB, vb[g * 4 + 1] * invB,
                  vb[g * 4 + 2] * invB, vb[g * 4 + 3] * invB);
    }
}

extern "C" void kernel_launch(void* const* d_in, const int* in_sizes, int n_in,
                              void* d_out, int out_size, void* d_ws, size_t ws_size,
                              hipStream_t stream) {
    const float* r = (const float*)d_in[0];
    float* out = (float*)d_out;
    double* part = (double*)((char*)d_ws + 64);

    stats_partial<<<NB * PB, 256, 0, stream>>>(r, part);
    attn_kernel<<<NB * 2048, 256, 0, stream>>>(r, part, out);
}